// Round 11
// baseline (233.755 us; speedup 1.0000x reference)
//
#include <hip/hip_runtime.h>

// n=2048 rows, f=32 features. Output row r = [emb[i] (32) | emb[j] (32) | sw[j]],
// i = r>>11, j = r&2047. Output = 2048*2048*65 floats = 1.09 GB, write-BW bound.
//
// v8b: sweep-ordered persistent kernel (fillBuffer's address pattern).
// (v8 + pipeline off-by-one fix: va2 refill must target iteration t+3, not
// t+2 — v8 repeated stale a-part values from t=2 onward, absmax 6.05.)
//
// Evidence: v2b..v7 exonerated barriers, convoys, loads/vmcnt order, nt flag,
// pre-store lgkm waits, and (mostly) wave count — all land at 5.0-5.4 TB/s.
// fillBufferAligned (6.5 TB/s, ~3.5 waves/CU) differs in ONE untested way:
// grid-stride order => the active set writes a compact ~1 MB stripe that
// sweeps, instead of our ~68 MB scattered instantaneous window. DRAM row-
// buffer locality is a function of the instantaneous address window.
//
// Structure: 256 blocks (1/CU) x 4 waves = 1024 waves. Wave W handles slabs
// slab(t) = W + 1024*t (t=0..255); slab = i*128 + jblk factorizes as
// jblk = W&127 (FIXED per wave -> b-part emb[j0..j0+15]+sw staged ONCE into
// both LDS images) and i = (W>>7) + 8t (a-part = 32 wave-uniform floats,
// rewritten per iteration into the alternate image, double-buffered).
// At every t the 1024 waves jointly write slabs [1024t,1024t+1024) = one
// contiguous 4.26 MB stripe sweeping the output linearly.
// 262,144 slabs = 1024 x 256 exactly -> no tail.

#define NROWS 2048u
#define SLAB_ROWS 16u
#define SLAB_FLOATS (SLAB_ROWS * 65u)        // 1040 floats = 4160 B
#define SLAB_F4 (SLAB_FLOATS / 4u)           // 260
#define NBLOCKS 256u
#define NWAVES (NBLOCKS * 4u)                // 1024
#define TOTAL_SLABS (NROWS * NROWS / SLAB_ROWS)  // 262144
#define ITERS (TOTAL_SLABS / NWAVES)         // 256

typedef float f32x4 __attribute__((ext_vector_type(4)));

__global__ __launch_bounds__(256) void expand_sweep(
    const float* __restrict__ emb,   // [2048*32]
    const float* __restrict__ sw,    // [2048]
    f32x4* __restrict__ out)         // flat output as float4
{
    __shared__ __align__(16) float lds[4][2][SLAB_FLOATS];   // 33,280 B

    const unsigned tid   = threadIdx.x;
    const unsigned wave  = tid >> 6;
    const unsigned lane  = tid & 63u;
    const unsigned W     = blockIdx.x * 4u + wave;     // 0..1023
    const unsigned j0    = (W & 127u) * SLAB_ROWS;     // fixed per wave
    const unsigned ibase = W >> 7;                     // i(t) = ibase + 8t
    const unsigned c     = lane & 31u;
    const unsigned rbase = (lane >> 5) * 8u;           // a-part rows

    float* img0 = &lds[wave][0][0];
    float* img1 = &lds[wave][1][0];

    // ---- stage b-part + sw into BOTH images (once per wave).
    {
        const f32x4* ej = (const f32x4*)(emb + (size_t)j0 * 32u);
        const f32x4 b0 = ej[lane];
        const f32x4 b1 = ej[lane + 64u];
        // global f4 g of slab -> float addr (g>>3)*65 + 32 + (g&7)*4.
        const unsigned d0 = (lane >> 3) * 65u + 32u + (lane & 7u) * 4u;
        img0[d0 + 0u] = b0.x; img0[d0 + 1u] = b0.y;
        img0[d0 + 2u] = b0.z; img0[d0 + 3u] = b0.w;
        img0[d0 + 520u] = b1.x; img0[d0 + 521u] = b1.y;
        img0[d0 + 522u] = b1.z; img0[d0 + 523u] = b1.w;
        img1[d0 + 0u] = b0.x; img1[d0 + 1u] = b0.y;
        img1[d0 + 2u] = b0.z; img1[d0 + 3u] = b0.w;
        img1[d0 + 520u] = b1.x; img1[d0 + 521u] = b1.y;
        img1[d0 + 522u] = b1.z; img1[d0 + 523u] = b1.w;
        if (lane < SLAB_ROWS) {
            const float s0 = sw[j0 + lane];
            img0[lane * 65u + 64u] = s0;
            img1[lane * 65u + 64u] = s0;
        }
    }

    // ---- a(0) into img0; prefetch a(1), a(2).
    float va1, va2;
    {
        const float va0 = emb[ibase * 32u + c];
#pragma unroll
        for (unsigned rp = 0; rp < 8u; ++rp)
            img0[(rbase + rp) * 65u + c] = va0;
        va1 = emb[(ibase + 8u) * 32u + c];      // i(1)
        va2 = emb[(ibase + 16u) * 32u + c];     // i(2)
    }

    // ---- main sweep: drain image(t) while building a(t+1) in the other.
    // Rotation invariant at top of iteration t: va1 = a(i(t+1)), va2 = a(i(t+2)).
    unsigned slab = W;
#pragma unroll 2
    for (unsigned t = 0; t < ITERS; ++t) {
        float* CUR = (t & 1u) ? img1 : img0;
        float* NXT = (t & 1u) ? img0 : img1;

        // drain CUR (slab t): 260 f4, unit stride, plain stores.
        const f32x4* L4 = (const f32x4*)CUR;
        const unsigned ob = slab * SLAB_F4;
#pragma unroll
        for (unsigned p = 0; p < 4u; ++p)
            out[ob + p * 64u + lane] = L4[p * 64u + lane];
        if (lane < 4u)
            out[ob + 256u + lane] = L4[256u + lane];

        // build a(t+1) in NXT (8 ds_writes; b-part already resident).
        if (t + 1u < ITERS) {
#pragma unroll
            for (unsigned rp = 0; rp < 8u; ++rp)
                NXT[(rbase + rp) * 65u + c] = va1;
        }
        va1 = va2;
        if (t + 3u < ITERS)                              // refill for i(t+3)
            va2 = emb[(ibase + (t + 3u) * 8u) * 32u + c];

        slab += NWAVES;
    }
}

extern "C" void kernel_launch(void* const* d_in, const int* in_sizes, int n_in,
                              void* d_out, int out_size, void* d_ws, size_t ws_size,
                              hipStream_t stream) {
    const float* emb = (const float*)d_in[0];   // [2048, 32] f32
    const float* sw  = (const float*)d_in[1];   // [2048] f32
    f32x4* out       = (f32x4*)d_out;

    expand_sweep<<<dim3(NBLOCKS), dim3(256), 0, stream>>>(emb, sw, out);
}

// Round 12
// 212.364 us; speedup vs baseline: 1.1007x; 1.1007x over previous
//
#include <hip/hip_runtime.h>

// n=2048 rows, f=32 features. Output row r = [emb[i] (32) | emb[j] (32) | sw[j]],
// i = r>>11, j = r&2047. Output = 2048*2048*65 floats = 1.09 GB, write-BW bound.
//
// v9: zero-LDS register-template kernel.
// Ladder v2b..v8b exonerated barriers, convoys, loads, nt, lgkm distance,
// wave count, sweep order — all LDS-drained schedules sit at 5.0-5.4 TB/s vs
// fillBuffer's 6.5. Last structural difference: fillBuffer stores immediate
// registers; we store LDS-read results. Here each wave fixes a j-slab
// (16 rows) and loops i over 128 values. Slab image = constant template
// (b-part emb[j0..j0+15] + sw[j0..], precomputed per lane as masked bits)
// merged with emb[i][*] at statically-known positions:
//     out_f4.k = uint_as_float((bits(av.k) & mk) | tb)   // 1 v_and_or_b32
// where av = this lane's a-run, one unaligned f4 load from emb[i] (L1
// broadcast: whole wave reads the same 128 B row). Loads are prefetched one
// i ahead (register banks A/B), so merges wait on L1 loads issued an
// iteration ago — the store stream has no LDS, no lgkm, no dependent waits.
// Rows i=0/2047 (shifted a-load would touch 3 floats OOB) use a clamped
// scalar path — wave-uniform, at most once per wave.
//
// Slot geometry (per lane L, slab f4 q = 64s+L, floats F=4q..4q+3,
// row=F/65, col=F%65): col<32 -> a (emb[i][col]); 32<=col<64 -> b
// (emb[(j0+row)*32+col-32]); col==64 -> sw[j0+row]. The a-run within a slot
// is contiguous and from one row, so av loaded at emb+i*32+(col-k) aligns
// component k with its target. Slot 4 (f4 256..259, lanes 0-3) covers cols
// 49..64 only -> pure constant C4, no load.
//
// Grid: 512 blocks x 4 waves = 2048 waves = 128 jslabs x 16 i-chunks. No
// LDS -> occupancy 2 blocks/CU (8 waves/CU, v7's sweet spot).

#define NROWS 2048u
#define SLAB_ROWS 16u
#define SLAB_F4 260u                    // (16*65)/4
#define ILEN 128u                       // i's per wave
#define NBLOCKS 512u
#define STRIDE_F4 (128u * SLAB_F4)      // f4 per i-step = 33280

typedef float f32x4 __attribute__((ext_vector_type(4)));
typedef f32x4 __attribute__((aligned(4))) f32x4u;   // dword-aligned f4 load

__global__ __launch_bounds__(256) void expand_reg(
    const float* __restrict__ emb,   // [2048*32]
    const float* __restrict__ sw,    // [2048]
    f32x4* __restrict__ out)         // flat output as float4
{
    const unsigned tid  = threadIdx.x;
    const unsigned lane = tid & 63u;
    const unsigned W =
        __builtin_amdgcn_readfirstlane(blockIdx.x * 4u + (tid >> 6));
    const unsigned jslab = W & 127u;          // fixed per wave
    const unsigned i0    = (W >> 7) * ILEN;   // 0,128,...,1920
    const unsigned j0    = jslab * SLAB_ROWS;

    // ---- prologue: per-slot template bits, a-masks, a-load offsets.
    unsigned tb[5][4];   // b/sw value bits; 0 at a-positions
    unsigned mk[5][4];   // 0xFFFFFFFF at a-positions
    int aoff[5];
#pragma unroll
    for (unsigned s = 0; s < 5u; ++s) {
        aoff[s] = 0;
        const unsigned q = (s < 4u) ? (s * 64u + lane) : (256u + (lane & 3u));
#pragma unroll
        for (unsigned k = 0; k < 4u; ++k) {
            const unsigned F = q * 4u + k;
            const unsigned r = F / 65u;
            const unsigned col = F - r * 65u;
            if (col < 32u) {
                tb[s][k] = 0u; mk[s][k] = 0xFFFFFFFFu;
                aoff[s] = (int)col - (int)k;
            } else if (col < 64u) {
                tb[s][k] = __float_as_uint(emb[(j0 + r) * 32u + (col - 32u)]);
                mk[s][k] = 0u;
            } else {
                tb[s][k] = __float_as_uint(sw[j0 + r]);
                mk[s][k] = 0u;
            }
        }
    }
    // slot 4 (cols 49..64) has no a-part -> constant.
    f32x4 C4;
    C4.x = __uint_as_float(tb[4][0]); C4.y = __uint_as_float(tb[4][1]);
    C4.z = __uint_as_float(tb[4][2]); C4.w = __uint_as_float(tb[4][3]);

    // clamped scalar a-load for boundary rows (i=0, i=2047).
    auto safe_ld = [&](int ao, unsigned ii) {
        f32x4 v;
#pragma unroll
        for (unsigned k = 0; k < 4u; ++k) {
            int c = ao + (int)k;
            c = c < 0 ? 0 : (c > 31 ? 31 : c);
            v[k] = emb[ii * 32u + (unsigned)c];
        }
        return v;
    };

#define FAST_LD(A0, A1, A2, A3, ii) {                                      \
        const float* ep = emb + (size_t)(ii) * 32u;                        \
        A0 = *(const f32x4u*)(ep + aoff[0]);                               \
        A1 = *(const f32x4u*)(ep + aoff[1]);                               \
        A2 = *(const f32x4u*)(ep + aoff[2]);                               \
        A3 = *(const f32x4u*)(ep + aoff[3]); }

#define SAFE_LD(A0, A1, A2, A3, ii) {                                      \
        A0 = safe_ld(aoff[0], (ii)); A1 = safe_ld(aoff[1], (ii));          \
        A2 = safe_ld(aoff[2], (ii)); A3 = safe_ld(aoff[3], (ii)); }

#define MRG(o, AV, S) {                                                    \
        o.x = __uint_as_float((__float_as_uint(AV.x) & mk[S][0]) | tb[S][0]); \
        o.y = __uint_as_float((__float_as_uint(AV.y) & mk[S][1]) | tb[S][1]); \
        o.z = __uint_as_float((__float_as_uint(AV.z) & mk[S][2]) | tb[S][2]); \
        o.w = __uint_as_float((__float_as_uint(AV.w) & mk[S][3]) | tb[S][3]); }

#define STORE5(A0, A1, A2, A3, OB) {                                       \
        f32x4 o0, o1, o2, o3;                                              \
        MRG(o0, A0, 0) MRG(o1, A1, 1) MRG(o2, A2, 2) MRG(o3, A3, 3)        \
        out[(OB) + lane]        = o0;                                      \
        out[(OB) + 64u + lane]  = o1;                                      \
        out[(OB) + 128u + lane] = o2;                                      \
        out[(OB) + 192u + lane] = o3;                                      \
        if (lane < 4u) out[(OB) + 256u + lane] = C4; }

    // ---- main loop: distance-1 prefetch, explicit banks, pairs of iters.
    f32x4 A0, A1, A2, A3, B0, B1, B2, B3;
    if (i0 == 0u) { SAFE_LD(A0, A1, A2, A3, 0u) }
    else          { FAST_LD(A0, A1, A2, A3, i0) }

    unsigned ob = (i0 * 128u + jslab) * SLAB_F4;

#pragma unroll 1
    for (unsigned t = 0; t < ILEN; t += 2u) {
        // iter t: prefetch i0+t+1 -> B, merge+store i0+t from A.
        const unsigned i1 = i0 + t + 1u;
        if (i1 == 2047u) { SAFE_LD(B0, B1, B2, B3, i1) }   // only chunk 15, t=126
        else             { FAST_LD(B0, B1, B2, B3, i1) }
        STORE5(A0, A1, A2, A3, ob)
        ob += STRIDE_F4;

        // iter t+1: prefetch i0+t+2 -> A (even row, never 2047), store B.
        if (t + 2u < ILEN) { FAST_LD(A0, A1, A2, A3, i0 + t + 2u) }
        STORE5(B0, B1, B2, B3, ob)
        ob += STRIDE_F4;
    }
#undef FAST_LD
#undef SAFE_LD
#undef MRG
#undef STORE5
}

extern "C" void kernel_launch(void* const* d_in, const int* in_sizes, int n_in,
                              void* d_out, int out_size, void* d_ws, size_t ws_size,
                              hipStream_t stream) {
    const float* emb = (const float*)d_in[0];   // [2048, 32] f32
    const float* sw  = (const float*)d_in[1];   // [2048] f32
    f32x4* out       = (f32x4*)d_out;

    expand_reg<<<dim3(NBLOCKS), dim3(256), 0, stream>>>(emb, sw, out);
}

// Round 13
// 202.972 us; speedup vs baseline: 1.1517x; 1.0463x over previous
//
#include <hip/hip_runtime.h>

// n=2048 rows, f=32 features. Output row r = [emb[i] (32) | emb[j] (32) | sw[j]],
// i = r>>11, j = r&2047. Output = 2048*2048*65 floats = 1.09 GB, write-BW bound.
//
// v7 (FINAL, best measured: 202.2 us = 5.40 TB/s effective write):
// intra-wave pipelined, double-buffered LDS, plain stores, 8 waves/CU via
// dynamic-LDS padding (61,440 B/block -> 2 blocks/CU).
//
// Ladder summary (all measured): v2b barrier-free 213; v3 pipelined 207;
// v4 load-free 228; v5 plain-stores 204; v6 reg-read-ahead 217; v7 202;
// v8b sweep-order 234; v9 zero-LDS 212. Model: dur = 1.09GB/6.55TB/s
// steady + ~35us fixed ramp (fits every variant AND fillBufferAligned's
// 4.36GB @ ~666us). The store-path structure is not the remaining limiter.

#define NROWS 2048u
#define BLOCK_ROWS 512u                 // per block (4 waves x 128 rows)
#define WAVE_ROWS 128u                  // per wave
#define SLAB_ROWS 16u
#define NSLABS 8u                       // 128/16
#define SLAB_FLOATS (SLAB_ROWS * 65u)   // 1040 floats = 4160 B
#define SLAB_F4 (SLAB_FLOATS / 4u)      // 260 float4, exact
#define LDS_BYTES 61440u                // pad -> 2 blocks/CU (160 KiB / CU)

typedef float f32x4 __attribute__((ext_vector_type(4)));

__global__ __launch_bounds__(256) void expand_pipe(
    const float* __restrict__ emb,   // [2048*32]
    const float* __restrict__ sw,    // [2048]
    f32x4* __restrict__ out)         // flat output as float4
{
    extern __shared__ __align__(16) float dynlds[];   // 61,440 B requested

    const unsigned tid  = threadIdx.x;
    const unsigned wave = tid >> 6;
    const unsigned lane = tid & 63u;

    // Wave's first output row. 128-aligned, 128 | 2048 -> i constant for the
    // whole wave, j-range j0..j0+127 contiguous (never wraps).
    const unsigned r0 = blockIdx.x * BLOCK_ROWS + wave * WAVE_ROWS;
    const unsigned i  = r0 >> 11;
    const unsigned j0 = r0 & (NROWS - 1u);

    // wave's two buffers, back to back.
    float* buf0 = dynlds + (wave * 2u + 0u) * SLAB_FLOATS;
    float* buf1 = dynlds + (wave * 2u + 1u) * SLAB_FLOATS;

    // ---- prologue: a-part. emb[i] is constant for all 128 rows: write cols
    // 0..31 of all 16 slab-rows into BOTH buffers once. Lanes 0-31 rows 0-7,
    // lanes 32-63 rows 8-15, col = lane&31.
    const float vi = emb[i * 32u + (lane & 31u)];
    const unsigned rbase = (lane >> 5) * 8u;
#pragma unroll
    for (unsigned rp = 0; rp < 8u; ++rp) {
        buf0[(rbase + rp) * 65u + (lane & 31u)] = vi;
        buf1[(rbase + rp) * 65u + (lane & 31u)] = vi;
    }

    // Static scatter destination for the b-part: global f4 index g in the
    // 128-f4 slab maps to LDS float addr (g>>3)*65 + 32 + (g&7)*4.
    // For g = lane+64 the addr is just d0 + 8*65.
    const unsigned d0 = (lane >> 3) * 65u + 32u + (lane & 7u) * 4u;

    // ---- prologue: prefetch + scatter slab 0 into buffer 0.
    {
        const f32x4* ej = (const f32x4*)(emb + (size_t)j0 * 32u);
        const f32x4 pa = ej[lane];
        const f32x4 pb = ej[lane + 64u];
        const float ps = sw[j0 + (lane & 15u)];
        buf0[d0 + 0u] = pa.x; buf0[d0 + 1u] = pa.y;
        buf0[d0 + 2u] = pa.z; buf0[d0 + 3u] = pa.w;
        buf0[d0 + 520u + 0u] = pb.x; buf0[d0 + 520u + 1u] = pb.y;
        buf0[d0 + 520u + 2u] = pb.z; buf0[d0 + 520u + 3u] = pb.w;
        if (lane < 16u) buf0[lane * 65u + 64u] = ps;
    }

    // ---- pipelined main loop over 8 slabs (fully unrolled, static buffers).
#pragma unroll
    for (unsigned s = 0; s < NSLABS; ++s) {
        float* CUR = (s & 1u) ? buf1 : buf0;
        float* NXT = (s & 1u) ? buf0 : buf1;

        // prefetch slab s+1 -> registers (independent of the drain below;
        // scheduler hoists the loads so latency hides under the stores)
        f32x4 pa, pb;
        float ps = 0.0f;
        if (s + 1u < NSLABS) {
            const f32x4* ej =
                (const f32x4*)(emb + (size_t)(j0 + (s + 1u) * SLAB_ROWS) * 32u);
            pa = ej[lane];
            pb = ej[lane + 64u];
            ps = sw[j0 + (s + 1u) * SLAB_ROWS + (lane & 15u)];
        }

        // drain buffer CUR (slab s): 260 float4, unit stride, plain stores.
        const f32x4* L4 = (const f32x4*)CUR;
        const unsigned obase = ((r0 + s * SLAB_ROWS) >> 4) * SLAB_F4;
#pragma unroll
        for (unsigned p = 0; p < 4u; ++p)
            out[obase + p * 64u + lane] = L4[p * 64u + lane];
        if (lane < 4u)
            out[obase + 256u + lane] = L4[256u + lane];

        // scatter prefetched slab s+1 into the other buffer.
        if (s + 1u < NSLABS) {
            NXT[d0 + 0u] = pa.x; NXT[d0 + 1u] = pa.y;
            NXT[d0 + 2u] = pa.z; NXT[d0 + 3u] = pa.w;
            NXT[d0 + 520u + 0u] = pb.x; NXT[d0 + 520u + 1u] = pb.y;
            NXT[d0 + 520u + 2u] = pb.z; NXT[d0 + 520u + 3u] = pb.w;
            if (lane < 16u) NXT[lane * 65u + 64u] = ps;
        }
    }
}

extern "C" void kernel_launch(void* const* d_in, const int* in_sizes, int n_in,
                              void* d_out, int out_size, void* d_ws, size_t ws_size,
                              hipStream_t stream) {
    const float* emb = (const float*)d_in[0];   // [2048, 32] f32
    const float* sw  = (const float*)d_in[1];   // [2048] f32
    f32x4* out       = (f32x4*)d_out;

    const unsigned blocks = (NROWS * NROWS) / BLOCK_ROWS;   // 8192
    expand_pipe<<<dim3(blocks), dim3(256), LDS_BYTES, stream>>>(emb, sw, out);
}